// Round 1
// baseline (1453.972 us; speedup 1.0000x reference)
//
#include <hip/hip_runtime.h>
#include <stdint.h>
#include <math.h>

#define USER_N 100000
#define NODE_N 150000
#define DD 64
#define NNZE 2400000
#define BB 4096
#define NLV 3
#define LF 32
#define HALF_SZ 196608u  /* (3*4096*32)/2 */

// ---------------- threefry2x32 (JAX original mode) ----------------
__host__ __device__ inline void tf_block(uint32_t k0, uint32_t k1, uint32_t& x0, uint32_t& x1) {
  uint32_t ks[3] = {k0, k1, k0 ^ k1 ^ 0x1BD11BDAu};
  x0 += ks[0]; x1 += ks[1];
  const int R0[4] = {13, 15, 26, 6};
  const int R1[4] = {17, 29, 16, 24};
#pragma unroll
  for (int i = 0; i < 5; ++i) {
    const int* R = (i & 1) ? R1 : R0;
#pragma unroll
    for (int j = 0; j < 4; ++j) {
      x0 += x1;
      x1 = (x1 << R[j]) | (x1 >> (32 - R[j]));
      x1 ^= x0;
    }
    x0 += ks[(i + 1) % 3];
    x1 += ks[(i + 2) % 3] + (uint32_t)(i + 1);
  }
}

__device__ inline float tf_uniform(uint32_t ka, uint32_t kb, uint32_t m) {
  uint32_t x0, x1;
  bool first = m < HALF_SZ;
  if (first) { x0 = m; x1 = m + HALF_SZ; } else { x0 = m - HALF_SZ; x1 = m; }
  tf_block(ka, kb, x0, x1);
  uint32_t bits = first ? x0 : x1;
  return __uint_as_float((bits >> 9) | 0x3f800000u) - 1.0f;
}

// ---------------- kernels ----------------
__global__ __launch_bounds__(256) void k_init(const float* __restrict__ ego,
                                              float* __restrict__ E, float* __restrict__ Esum) {
  int i = blockIdx.x * 256 + threadIdx.x;
  float v = ego[i];
  E[i] = v; Esum[i] = v;
}

__global__ __launch_bounds__(256) void k_hist(const int* __restrict__ rows, int* __restrict__ counts) {
  int e = blockIdx.x * 256 + threadIdx.x;
  if (e < NNZE) atomicAdd(&counts[rows[e]], 1);
}

__global__ __launch_bounds__(1024) void k_scan1(const int* __restrict__ counts,
                                                int* __restrict__ rs1, int* __restrict__ bsums) {
  __shared__ int buf[1024];
  int t = threadIdx.x;
  int i = blockIdx.x * 1024 + t;
  int v = (i < NODE_N) ? counts[i] : 0;
  buf[t] = v;
  __syncthreads();
  for (int off = 1; off < 1024; off <<= 1) {
    int add = (t >= off) ? buf[t - off] : 0;
    __syncthreads();
    buf[t] += add;
    __syncthreads();
  }
  if (i < NODE_N) rs1[i] = buf[t];
  if (t == 1023) bsums[blockIdx.x] = buf[1023];
}

__global__ __launch_bounds__(256) void k_scan2(int* __restrict__ bsums, int nb) {
  __shared__ int buf[256];
  int t = threadIdx.x;
  int v = (t < nb) ? bsums[t] : 0;
  buf[t] = v;
  __syncthreads();
  for (int off = 1; off < 256; off <<= 1) {
    int add = (t >= off) ? buf[t - off] : 0;
    __syncthreads();
    buf[t] += add;
    __syncthreads();
  }
  if (t < nb) bsums[t] = buf[t] - v;  // exclusive
}

__global__ __launch_bounds__(1024) void k_scan3(int* __restrict__ row_start,
                                                int* __restrict__ cursor,
                                                const int* __restrict__ bsums) {
  int i = blockIdx.x * 1024 + threadIdx.x;
  if (i < NODE_N) {
    int v = row_start[i + 1] + bsums[blockIdx.x];
    row_start[i + 1] = v;
    cursor[i + 1] = v;
  }
  if (i == 0) { row_start[0] = 0; cursor[0] = 0; }
}

__global__ __launch_bounds__(256) void k_scatter(const int* __restrict__ rows,
                                                 const int* __restrict__ cols,
                                                 const float* __restrict__ vals,
                                                 int* __restrict__ cursor,
                                                 float* __restrict__ svals, int* __restrict__ scols) {
  int e = blockIdx.x * 256 + threadIdx.x;
  if (e < NNZE) {
    int r = rows[e];
    int p = atomicAdd(&cursor[r], 1);
    svals[p] = vals[e];
    scols[p] = cols[e];
  }
}

__global__ __launch_bounds__(256) void k_spmm(const float* __restrict__ E,
                                              const float* __restrict__ svals,
                                              const int* __restrict__ scols,
                                              const int* __restrict__ row_start,
                                              float* __restrict__ side) {
  int r = blockIdx.x * 4 + (threadIdx.x >> 6);
  int lane = threadIdx.x & 63;
  int rs = row_start[r], re = row_start[r + 1];
  float acc = 0.f;
  int e = rs;
  for (; e + 1 < re; e += 2) {
    int c0 = scols[e], c1 = scols[e + 1];
    float v0 = svals[e], v1 = svals[e + 1];
    float a0 = E[(size_t)c0 * DD + lane];
    float a1 = E[(size_t)c1 * DD + lane];
    acc += v0 * a0;
    acc += v1 * a1;
  }
  if (e < re) acc += svals[e] * E[(size_t)scols[e] * DD + lane];
  side[(size_t)r * DD + lane] = acc;
}

__global__ __launch_bounds__(256) void k_transform(const float* __restrict__ gw,
                                                   const float* __restrict__ gb,
                                                   const float* __restrict__ bw,
                                                   const float* __restrict__ bb,
                                                   float* __restrict__ E, float* __restrict__ Esum,
                                                   const float* __restrict__ side) {
  int r = blockIdx.x * 4 + (threadIdx.x >> 6);
  int lane = threadIdx.x & 63;
  size_t o = (size_t)r * DD + lane;
  float s = side[o];
  float e = E[o];
  float p = e * s;
  float a1 = gb[lane], a2 = bb[lane];
#pragma unroll 8
  for (int k = 0; k < 64; ++k) {
    float sk = __shfl(s, k, 64);
    float pk = __shfl(p, k, 64);
    a1 += sk * gw[k * 64 + lane];
    a2 += pk * bw[k * 64 + lane];
  }
  a1 = (a1 > 0.f) ? a1 : 0.01f * a1;
  a2 = (a2 > 0.f) ? a2 : 0.01f * a2;
  float v = a1 + a2;
  float ss = v * v;
#pragma unroll
  for (int off = 32; off; off >>= 1) ss += __shfl_xor(ss, off, 64);
  v = v / fmaxf(sqrtf(ss), 1e-12f);
  E[o] = v;
  Esum[o] += v;
}

__global__ __launch_bounds__(128) void k_gather(const float* __restrict__ Esum,
                                                const int* __restrict__ uid,
                                                const int* __restrict__ iid,
                                                float* __restrict__ ue, float* __restrict__ ie) {
  int b = blockIdx.x, t = threadIdx.x;
  if (t < 64) ue[(size_t)b * 64 + t] = Esum[(size_t)uid[b] * 64 + t];
  else {
    int d = t - 64;
    ie[(size_t)b * 64 + d] = Esum[(size_t)(USER_N + iid[b]) * 64 + d];
  }
}

__global__ __launch_bounds__(256) void k_encoder(const float* __restrict__ xin,
                                                 const float* __restrict__ hw, const float* __restrict__ hb,
                                                 const float* __restrict__ w1, const float* __restrict__ b1,
                                                 const float* __restrict__ w2, const float* __restrict__ b2,
                                                 float* __restrict__ recs) {
  __shared__ float sx[64], sreps[64], st[256];
  int b = blockIdx.x, l = blockIdx.y, t = threadIdx.x;
  if (t < 64) sx[t] = xin[(size_t)b * 64 + t];
  __syncthreads();
  if (t < 64) {
    const float* W = hw + l * 64 * 64;
    float a = hb[l * 64 + t];
#pragma unroll 8
    for (int k = 0; k < 64; ++k) a += sx[k] * W[k * 64 + t];
    sreps[t] = tanhf(a);
  }
  __syncthreads();
  {
    const float* W = w1 + l * 64 * 256;
    float a = b1[l * 256 + t];
#pragma unroll 8
    for (int k = 0; k < 64; ++k) a += sreps[k] * W[k * 256 + t];
    st[t] = tanhf(a);
  }
  __syncthreads();
  if (t < 32) {
    const float* W = w2 + l * 256 * 32;
    float a = b2[l * 32 + t];
#pragma unroll 8
    for (int k = 0; k < 256; ++k) a += st[k] * W[k * 32 + t];
    recs[((size_t)l * BB + b) * 32 + t] = a;
  }
}

__global__ __launch_bounds__(256) void k_attn(const float* __restrict__ recs,
                                              const float* __restrict__ qw, const float* __restrict__ qb,
                                              const float* __restrict__ kw, const float* __restrict__ kb,
                                              const float* __restrict__ vw, const float* __restrict__ vb,
                                              float* __restrict__ att) {
  int t = threadIdx.x;
  int b = blockIdx.x * 8 + (t >> 5);
  int d = t & 31;
  float x0 = recs[((size_t)0 * BB + b) * 32 + d];
  float x1 = recs[((size_t)1 * BB + b) * 32 + d];
  float x2 = recs[((size_t)2 * BB + b) * 32 + d];
  float q0 = qb[d], q1 = q0, q2 = q0;
  float c0 = kb[d], c1 = c0, c2 = c0;
  float v0 = vb[d], v1 = v0, v2 = v0;
#pragma unroll 4
  for (int kk = 0; kk < 32; ++kk) {
    float xa = __shfl(x0, kk, 32);
    float xb = __shfl(x1, kk, 32);
    float xc = __shfl(x2, kk, 32);
    float wq = qw[kk * 32 + d], wk = kw[kk * 32 + d], wv = vw[kk * 32 + d];
    q0 += xa * wq; q1 += xb * wq; q2 += xc * wq;
    c0 += xa * wk; c1 += xb * wk; c2 += xc * wk;
    v0 += xa * wv; v1 += xb * wv; v2 += xc * wv;
  }
  float qs[3] = {q0, q1, q2}, ks[3] = {c0, c1, c2}, vs[3] = {v0, v1, v2};
  float sc[3][3];
#pragma unroll
  for (int s = 0; s < 3; ++s)
#pragma unroll
    for (int u = 0; u < 3; ++u) {
      float p = qs[s] * ks[u];
#pragma unroll
      for (int off = 16; off; off >>= 1) p += __shfl_xor(p, off, 32);
      sc[s][u] = p * 0.17677669529663687f;  // 1/sqrt(32)
    }
#pragma unroll
  for (int s = 0; s < 3; ++s) {
    float m = fmaxf(sc[s][0], fmaxf(sc[s][1], sc[s][2]));
    float e0 = __expf(sc[s][0] - m), e1 = __expf(sc[s][1] - m), e2 = __expf(sc[s][2] - m);
    float inv = 1.f / (e0 + e1 + e2);
    att[(size_t)b * 96 + s * 32 + d] = (e0 * vs[0] + e1 * vs[1] + e2 * vs[2]) * inv;
  }
}

__global__ __launch_bounds__(256) void k_noise(const float* __restrict__ att_u,
                                               const float* __restrict__ att_i,
                                               uint32_t ku0, uint32_t ku1, uint32_t ki0, uint32_t ki1,
                                               float* __restrict__ n1, float* __restrict__ n2,
                                               float* __restrict__ posdot) {
  int t = threadIdx.x;
  int g = blockIdx.x * 8 + (t >> 5);   // [0, 24576)
  int k = t & 31;
  int side = g / (NLV * BB);
  int rem = g - side * (NLV * BB);
  int l = rem >> 12;
  int b = rem & 4095;
  const float* att = side ? att_i : att_u;
  uint32_t ka = side ? ki0 : ku0;
  uint32_t kb = side ? ki1 : ku1;
  float r = att[(size_t)b * 96 + l * 32 + k];
  float ss = r * r;
#pragma unroll
  for (int off = 16; off; off >>= 1) ss += __shfl_xor(ss, off, 32);
  float v1 = r / fmaxf(sqrtf(ss), 1e-12f);
  uint32_t m = ((uint32_t)(l * BB + b)) * 32u + (uint32_t)k;
  float u = tf_uniform(ka, kb, m);
  float us = u * u;
#pragma unroll
  for (int off = 16; off; off >>= 1) us += __shfl_xor(us, off, 32);
  float un = u / fmaxf(sqrtf(us), 1e-12f);
  float sgn = (r > 0.f) ? 1.f : ((r < 0.f) ? -1.f : 0.f);
  float rn = r + sgn * un * 0.1f;
  float s2 = rn * rn;
#pragma unroll
  for (int off = 16; off; off >>= 1) s2 += __shfl_xor(s2, off, 32);
  float v2 = rn / fmaxf(sqrtf(s2), 1e-12f);
  float pd = v1 * v2;
#pragma unroll
  for (int off = 16; off; off >>= 1) pd += __shfl_xor(pd, off, 32);
  size_t o = (size_t)g * 32 + k;
  n1[o] = v1;
  n2[o] = v2;
  if (k == 0) posdot[g] = pd;
}

__global__ __launch_bounds__(256) void k_ttl(const float* __restrict__ n1,
                                             const float* __restrict__ n2,
                                             float* __restrict__ ttl) {
  __shared__ float sj[128][32];
  int sl = blockIdx.z;
  int t = threadIdx.x;
  int i = blockIdx.x * 256 + t;
  int j0 = blockIdx.y * 128;
  const float* n1b = n1 + (size_t)sl * BB * 32;
  const float* n2b = n2 + (size_t)sl * BB * 32;
  for (int idx = t; idx < 128 * 32; idx += 256) sj[idx >> 5][idx & 31] = n2b[(size_t)j0 * 32 + idx];
  __syncthreads();
  float r[32];
#pragma unroll
  for (int k = 0; k < 32; ++k) r[k] = n1b[(size_t)i * 32 + k];
  float acc = 0.f;
  for (int j = 0; j < 128; ++j) {
    float dot = 0.f;
#pragma unroll
    for (int k = 0; k < 32; ++k) dot += r[k] * sj[j][k];
    acc += __expf(dot * 5.0f);  // 1/TAU = 5
  }
  atomicAdd(&ttl[sl * BB + i], acc);
}

__global__ __launch_bounds__(1024) void k_clred(const float* __restrict__ ttl,
                                                const float* __restrict__ posdot,
                                                float* __restrict__ outp) {
  __shared__ float red[1024];
  int t = threadIdx.x;
  float a = 0.f;
  for (int idx = t; idx < 6 * BB; idx += 1024)
    a += logf(ttl[idx]) - posdot[idx] * 5.0f;
  red[t] = a;
  __syncthreads();
  for (int off = 512; off; off >>= 1) {
    if (t < off) red[t] += red[t + off];
    __syncthreads();
  }
  if (t == 0) outp[2 * BB] = red[0] * (1.f / 12288.f);  // (cl_u + cl_i)
}

__global__ __launch_bounds__(256) void k_head(const float* __restrict__ att_u,
                                              const float* __restrict__ att_i,
                                              const float* __restrict__ skills,
                                              const float* __restrict__ w1, const float* __restrict__ b1,
                                              const float* __restrict__ w2, const float* __restrict__ b2,
                                              const float* __restrict__ pw, const float* __restrict__ pb,
                                              float* __restrict__ outp) {
  __shared__ float diag[4][96], t1[4][64];
  int t = threadIdx.x;
  int w = t >> 6, lane = t & 63;
  int b = blockIdx.x * 4 + w;
  for (int j = lane; j < 96; j += 64) {
    float su = 1.f / (1.f + __expf(-att_u[(size_t)b * 96 + j]));
    float si = 1.f / (1.f + __expf(-att_i[(size_t)b * 96 + j]));
    diag[w][j] = (su - si) * skills[(size_t)b * 96 + j];
  }
  __syncthreads();
  float a = b1[lane];
#pragma unroll 8
  for (int j = 0; j < 96; ++j) a += diag[w][j] * w1[j * 64 + lane];
  t1[w][lane] = tanhf(a);
  __syncthreads();
  float h = b2[lane];
#pragma unroll 8
  for (int kk = 0; kk < 64; ++kk) h += t1[w][kk] * w2[kk * 64 + lane];
  float p0 = h * pw[lane * 2 + 0];
  float p1 = h * pw[lane * 2 + 1];
#pragma unroll
  for (int off = 32; off; off >>= 1) {
    p0 += __shfl_xor(p0, off, 64);
    p1 += __shfl_xor(p1, off, 64);
  }
  if (lane == 0) {
    float l0 = p0 + pb[0], l1 = p1 + pb[1];
    float m = fmaxf(l0, l1);
    float e0 = __expf(l0 - m), e1 = __expf(l1 - m);
    float inv = 1.f / (e0 + e1);
    outp[(size_t)b * 2 + 0] = e0 * inv;
    outp[(size_t)b * 2 + 1] = e1 * inv;
  }
}

// ---------------- launcher ----------------
extern "C" void kernel_launch(void* const* d_in, const int* in_sizes, int n_in,
                              void* d_out, int out_size, void* d_ws, size_t ws_size,
                              hipStream_t stream) {
  const float* ego    = (const float*)d_in[0];
  const float* gc_w   = (const float*)d_in[1];
  const float* gc_b   = (const float*)d_in[2];
  const float* bi_w   = (const float*)d_in[3];
  const float* bi_b   = (const float*)d_in[4];
  const float* uh_w   = (const float*)d_in[5];
  const float* uh_b   = (const float*)d_in[6];
  const float* ih_w   = (const float*)d_in[7];
  const float* ih_b   = (const float*)d_in[8];
  const float* ud_w1  = (const float*)d_in[9];
  const float* ud_b1  = (const float*)d_in[10];
  const float* ud_w2  = (const float*)d_in[11];
  const float* ud_b2  = (const float*)d_in[12];
  const float* id_w1  = (const float*)d_in[13];
  const float* id_b1  = (const float*)d_in[14];
  const float* id_w2  = (const float*)d_in[15];
  const float* id_b2  = (const float*)d_in[16];
  const float* q_w    = (const float*)d_in[17];
  const float* q_b    = (const float*)d_in[18];
  const float* k_w    = (const float*)d_in[19];
  const float* k_b    = (const float*)d_in[20];
  const float* v_w    = (const float*)d_in[21];
  const float* v_b    = (const float*)d_in[22];
  const float* dg_w1  = (const float*)d_in[23];
  const float* dg_b1  = (const float*)d_in[24];
  const float* dg_w2  = (const float*)d_in[25];
  const float* dg_b2  = (const float*)d_in[26];
  const float* pr_w   = (const float*)d_in[27];
  const float* pr_b   = (const float*)d_in[28];
  const float* adj_vals = (const float*)d_in[29];
  const float* skills = (const float*)d_in[30];
  const int* user_id  = (const int*)d_in[31];
  const int* item_id  = (const int*)d_in[32];
  const int* adj_rows = (const int*)d_in[33];
  const int* adj_cols = (const int*)d_in[34];
  float* outp = (float*)d_out;

  char* w = (char*)d_ws;
  auto alloc = [&](size_t bytes) -> char* {
    char* p = w;
    w += (bytes + 255) & ~(size_t)255;
    return p;
  };
  float* E      = (float*)alloc((size_t)NODE_N * DD * 4);
  float* Esum   = (float*)alloc((size_t)NODE_N * DD * 4);
  float* side   = (float*)alloc((size_t)NODE_N * DD * 4);
  float* svals  = (float*)alloc((size_t)NNZE * 4);
  int*   scols  = (int*)  alloc((size_t)NNZE * 4);
  int*   counts = (int*)  alloc((size_t)NODE_N * 4);
  int*   row_start = (int*)alloc((size_t)(NODE_N + 1) * 4);
  int*   cursor = (int*)  alloc((size_t)(NODE_N + 1) * 4);
  int*   bsums  = (int*)  alloc(256 * 4);
  float* ue     = (float*)alloc((size_t)BB * 64 * 4);
  float* ie     = (float*)alloc((size_t)BB * 64 * 4);
  float* recs_u = (float*)alloc((size_t)NLV * BB * 32 * 4);
  float* recs_i = (float*)alloc((size_t)NLV * BB * 32 * 4);
  float* att_u  = (float*)alloc((size_t)BB * 96 * 4);
  float* att_i  = (float*)alloc((size_t)BB * 96 * 4);
  float* n1     = (float*)alloc((size_t)6 * BB * 32 * 4);
  float* n2     = (float*)alloc((size_t)6 * BB * 32 * 4);
  float* posdot = (float*)alloc((size_t)6 * BB * 4);
  float* ttl    = (float*)alloc((size_t)6 * BB * 4);

  // host-side: kc = jax.random.split(jax.random.key(42), 2)
  // counts [0,1,2,3] -> blocks (0,2) and (1,3); kc0=(o0_blk0,o0_blk1), kc1=(o1_blk0,o1_blk1)
  uint32_t a0 = 0, a1 = 2, b0 = 1, b1 = 3;
  tf_block(0u, 42u, a0, a1);
  tf_block(0u, 42u, b0, b1);
  uint32_t ku0 = a0, ku1 = b0;   // kc[0] -> u side
  uint32_t ki0 = a1, ki1 = b1;   // kc[1] -> i side

  hipMemsetAsync(counts, 0, (size_t)NODE_N * 4, stream);
  hipMemsetAsync(ttl, 0, (size_t)6 * BB * 4, stream);

  k_init<<<37500, 256, 0, stream>>>(ego, E, Esum);
  k_hist<<<9375, 256, 0, stream>>>(adj_rows, counts);
  k_scan1<<<147, 1024, 0, stream>>>(counts, row_start + 1, bsums);
  k_scan2<<<1, 256, 0, stream>>>(bsums, 147);
  k_scan3<<<147, 1024, 0, stream>>>(row_start, cursor, bsums);
  k_scatter<<<9375, 256, 0, stream>>>(adj_rows, adj_cols, adj_vals, cursor, svals, scols);

  for (int l = 0; l < 2; ++l) {
    k_spmm<<<37500, 256, 0, stream>>>(E, svals, scols, row_start, side);
    k_transform<<<37500, 256, 0, stream>>>(gc_w + l * 4096, gc_b + l * 64,
                                           bi_w + l * 4096, bi_b + l * 64,
                                           E, Esum, side);
  }

  k_gather<<<4096, 128, 0, stream>>>(Esum, user_id, item_id, ue, ie);

  dim3 ge(4096, 3);
  k_encoder<<<ge, 256, 0, stream>>>(ue, uh_w, uh_b, ud_w1, ud_b1, ud_w2, ud_b2, recs_u);
  k_encoder<<<ge, 256, 0, stream>>>(ie, ih_w, ih_b, id_w1, id_b1, id_w2, id_b2, recs_i);

  k_attn<<<512, 256, 0, stream>>>(recs_u, q_w, q_b, k_w, k_b, v_w, v_b, att_u);
  k_attn<<<512, 256, 0, stream>>>(recs_i, q_w, q_b, k_w, k_b, v_w, v_b, att_i);

  k_noise<<<3072, 256, 0, stream>>>(att_u, att_i, ku0, ku1, ki0, ki1, n1, n2, posdot);

  dim3 gt(16, 32, 6);
  k_ttl<<<gt, 256, 0, stream>>>(n1, n2, ttl);
  k_clred<<<1, 1024, 0, stream>>>(ttl, posdot, outp);

  k_head<<<1024, 256, 0, stream>>>(att_u, att_i, skills, dg_w1, dg_b1, dg_w2, dg_b2,
                                   pr_w, pr_b, outp);
}

// Round 2
// 1173.359 us; speedup vs baseline: 1.2392x; 1.2392x over previous
//
#include <hip/hip_runtime.h>
#include <stdint.h>
#include <math.h>

#define USER_N 100000
#define NODE_N 150000
#define DD 64
#define NNZE 2400000
#define BB 4096
#define NLV 3
#define LF 32
#define HALF_SZ 196608u  /* (3*4096*32)/2 */

// ---------------- threefry2x32 (JAX original mode) ----------------
__host__ __device__ inline void tf_block(uint32_t k0, uint32_t k1, uint32_t& x0, uint32_t& x1) {
  uint32_t ks[3] = {k0, k1, k0 ^ k1 ^ 0x1BD11BDAu};
  x0 += ks[0]; x1 += ks[1];
  const int R0[4] = {13, 15, 26, 6};
  const int R1[4] = {17, 29, 16, 24};
#pragma unroll
  for (int i = 0; i < 5; ++i) {
    const int* R = (i & 1) ? R1 : R0;
#pragma unroll
    for (int j = 0; j < 4; ++j) {
      x0 += x1;
      x1 = (x1 << R[j]) | (x1 >> (32 - R[j]));
      x1 ^= x0;
    }
    x0 += ks[(i + 1) % 3];
    x1 += ks[(i + 2) % 3] + (uint32_t)(i + 1);
  }
}

__device__ inline float tf_uniform(uint32_t ka, uint32_t kb, uint32_t m) {
  uint32_t x0, x1;
  bool first = m < HALF_SZ;
  if (first) { x0 = m; x1 = m + HALF_SZ; } else { x0 = m - HALF_SZ; x1 = m; }
  tf_block(ka, kb, x0, x1);
  uint32_t bits = first ? x0 : x1;
  return __uint_as_float((bits >> 9) | 0x3f800000u) - 1.0f;
}

// ---------------- kernels ----------------
__global__ __launch_bounds__(256) void k_init(const float* __restrict__ ego,
                                              float* __restrict__ E, float* __restrict__ Esum) {
  int i = blockIdx.x * 256 + threadIdx.x;
  float v = ego[i];
  E[i] = v; Esum[i] = v;
}

__global__ __launch_bounds__(256) void k_hist(const int* __restrict__ rows, int* __restrict__ counts) {
  int e = blockIdx.x * 256 + threadIdx.x;
  if (e < NNZE) atomicAdd(&counts[rows[e]], 1);
}

__global__ __launch_bounds__(1024) void k_scan1(const int* __restrict__ counts,
                                                int* __restrict__ rs1, int* __restrict__ bsums) {
  __shared__ int buf[1024];
  int t = threadIdx.x;
  int i = blockIdx.x * 1024 + t;
  int v = (i < NODE_N) ? counts[i] : 0;
  buf[t] = v;
  __syncthreads();
  for (int off = 1; off < 1024; off <<= 1) {
    int add = (t >= off) ? buf[t - off] : 0;
    __syncthreads();
    buf[t] += add;
    __syncthreads();
  }
  if (i < NODE_N) rs1[i] = buf[t];
  if (t == 1023) bsums[blockIdx.x] = buf[1023];
}

__global__ __launch_bounds__(256) void k_scan2(int* __restrict__ bsums, int nb) {
  __shared__ int buf[256];
  int t = threadIdx.x;
  int v = (t < nb) ? bsums[t] : 0;
  buf[t] = v;
  __syncthreads();
  for (int off = 1; off < 256; off <<= 1) {
    int add = (t >= off) ? buf[t - off] : 0;
    __syncthreads();
    buf[t] += add;
    __syncthreads();
  }
  if (t < nb) bsums[t] = buf[t] - v;  // exclusive
}

__global__ __launch_bounds__(1024) void k_scan3(int* __restrict__ row_start,
                                                int* __restrict__ cursor,
                                                const int* __restrict__ bsums) {
  int i = blockIdx.x * 1024 + threadIdx.x;
  if (i < NODE_N) {
    int v = row_start[i + 1] + bsums[blockIdx.x];
    row_start[i + 1] = v;
    cursor[i + 1] = v;
  }
  if (i == 0) { row_start[0] = 0; cursor[0] = 0; }
}

__global__ __launch_bounds__(256) void k_scatter(const int* __restrict__ rows,
                                                 const int* __restrict__ cols,
                                                 const float* __restrict__ vals,
                                                 int* __restrict__ cursor,
                                                 float* __restrict__ svals, int* __restrict__ scols) {
  int e = blockIdx.x * 256 + threadIdx.x;
  if (e < NNZE) {
    int r = rows[e];
    int p = atomicAdd(&cursor[r], 1);
    svals[p] = vals[e];
    scols[p] = cols[e];
  }
}

// wave-per-row SpMM, 4x unrolled edge loop for memory-level parallelism
__global__ __launch_bounds__(256) void k_spmm(const float* __restrict__ E,
                                              const float* __restrict__ svals,
                                              const int* __restrict__ scols,
                                              const int* __restrict__ row_start,
                                              float* __restrict__ side) {
  int r = blockIdx.x * 4 + (threadIdx.x >> 6);
  int lane = threadIdx.x & 63;
  int rs = row_start[r], re = row_start[r + 1];
  float acc = 0.f;
  int e = rs;
  for (; e + 4 <= re; e += 4) {
    int c0 = scols[e], c1 = scols[e + 1], c2 = scols[e + 2], c3 = scols[e + 3];
    float v0 = svals[e], v1 = svals[e + 1], v2 = svals[e + 2], v3 = svals[e + 3];
    float a0 = E[(size_t)c0 * DD + lane];
    float a1 = E[(size_t)c1 * DD + lane];
    float a2 = E[(size_t)c2 * DD + lane];
    float a3 = E[(size_t)c3 * DD + lane];
    acc = fmaf(v0, a0, acc);
    acc = fmaf(v1, a1, acc);
    acc = fmaf(v2, a2, acc);
    acc = fmaf(v3, a3, acc);
  }
  for (; e < re; ++e) acc = fmaf(svals[e], E[(size_t)scols[e] * DD + lane], acc);
  side[(size_t)r * DD + lane] = acc;
}

// Transform: weights held in VGPR columns, row vectors broadcast from LDS via b128.
// Replaces the 128-shuffles-per-row structure that was LDS-pipe-bound (248us, VALUBusy 24%).
#define TR_ROWS 16
#define TR_GRID 1875   /* 9375 chunks / 5 per block */
__global__ __launch_bounds__(256) void k_transform(const float* __restrict__ gw,
                                                   const float* __restrict__ gb,
                                                   const float* __restrict__ bw,
                                                   const float* __restrict__ bb,
                                                   float* __restrict__ E, float* __restrict__ Esum,
                                                   const float* __restrict__ side) {
  __shared__ float ss[TR_ROWS][64];
  __shared__ float pp[TR_ROWS][64];
  int t = threadIdx.x;
  int lane = t & 63;
  int wv = t >> 6;
  // each thread caches weight column `lane` (identical across the 4 waves)
  float wgr[64], wbr[64];
#pragma unroll
  for (int k = 0; k < 64; ++k) {
    wgr[k] = gw[k * 64 + lane];
    wbr[k] = bw[k * 64 + lane];
  }
  float gbl = gb[lane], bbl = bb[lane];
  const int nchunks = NODE_N / TR_ROWS;  // 9375
  for (int chunk = blockIdx.x; chunk < nchunks; chunk += TR_GRID) {
    int r0 = chunk * TR_ROWS;
    {
      // stage 16 rows x 64 floats; thread t loads one float4 (coalesced)
      int row = t >> 4;
      int col = (t & 15) * 4;
      float4 sv = *(const float4*)&side[(size_t)(r0 + row) * 64 + col];
      float4 ev = *(const float4*)&E[(size_t)(r0 + row) * 64 + col];
      *(float4*)&ss[row][col] = sv;
      pp[row][col + 0] = sv.x * ev.x;
      pp[row][col + 1] = sv.y * ev.y;
      pp[row][col + 2] = sv.z * ev.z;
      pp[row][col + 3] = sv.w * ev.w;
    }
    __syncthreads();
#pragma unroll
    for (int rr = 0; rr < 4; ++rr) {
      int row = wv + rr * 4;
      float a10 = 0.f, a11 = 0.f, a12 = 0.f, a13 = 0.f;
      float a20 = 0.f, a21 = 0.f, a22 = 0.f, a23 = 0.f;
#pragma unroll
      for (int k = 0; k < 64; k += 4) {
        float4 s4 = *(const float4*)&ss[row][k];   // wave-uniform -> LDS broadcast
        float4 p4 = *(const float4*)&pp[row][k];
        a10 = fmaf(s4.x, wgr[k + 0], a10);
        a11 = fmaf(s4.y, wgr[k + 1], a11);
        a12 = fmaf(s4.z, wgr[k + 2], a12);
        a13 = fmaf(s4.w, wgr[k + 3], a13);
        a20 = fmaf(p4.x, wbr[k + 0], a20);
        a21 = fmaf(p4.y, wbr[k + 1], a21);
        a22 = fmaf(p4.z, wbr[k + 2], a22);
        a23 = fmaf(p4.w, wbr[k + 3], a23);
      }
      float a1 = gbl + ((a10 + a11) + (a12 + a13));
      float a2 = bbl + ((a20 + a21) + (a22 + a23));
      a1 = (a1 > 0.f) ? a1 : 0.01f * a1;
      a2 = (a2 > 0.f) ? a2 : 0.01f * a2;
      float v = a1 + a2;
      float sq = v * v;
#pragma unroll
      for (int off = 32; off; off >>= 1) sq += __shfl_xor(sq, off, 64);
      v = v / fmaxf(sqrtf(sq), 1e-12f);
      size_t o = (size_t)(r0 + row) * 64 + lane;
      E[o] = v;
      Esum[o] += v;
    }
    __syncthreads();
  }
}

__global__ __launch_bounds__(128) void k_gather(const float* __restrict__ Esum,
                                                const int* __restrict__ uid,
                                                const int* __restrict__ iid,
                                                float* __restrict__ ue, float* __restrict__ ie) {
  int b = blockIdx.x, t = threadIdx.x;
  if (t < 64) ue[(size_t)b * 64 + t] = Esum[(size_t)uid[b] * 64 + t];
  else {
    int d = t - 64;
    ie[(size_t)b * 64 + d] = Esum[(size_t)(USER_N + iid[b]) * 64 + d];
  }
}

__global__ __launch_bounds__(256) void k_encoder(const float* __restrict__ xin,
                                                 const float* __restrict__ hw, const float* __restrict__ hb,
                                                 const float* __restrict__ w1, const float* __restrict__ b1,
                                                 const float* __restrict__ w2, const float* __restrict__ b2,
                                                 float* __restrict__ recs) {
  __shared__ float sx[64], sreps[64], st[256];
  int b = blockIdx.x, l = blockIdx.y, t = threadIdx.x;
  if (t < 64) sx[t] = xin[(size_t)b * 64 + t];
  __syncthreads();
  if (t < 64) {
    const float* W = hw + l * 64 * 64;
    float a = hb[l * 64 + t];
#pragma unroll 8
    for (int k = 0; k < 64; ++k) a += sx[k] * W[k * 64 + t];
    sreps[t] = tanhf(a);
  }
  __syncthreads();
  {
    const float* W = w1 + l * 64 * 256;
    float a = b1[l * 256 + t];
#pragma unroll 8
    for (int k = 0; k < 64; ++k) a += sreps[k] * W[k * 256 + t];
    st[t] = tanhf(a);
  }
  __syncthreads();
  if (t < 32) {
    const float* W = w2 + l * 256 * 32;
    float a = b2[l * 32 + t];
#pragma unroll 8
    for (int k = 0; k < 256; ++k) a += st[k] * W[k * 32 + t];
    recs[((size_t)l * BB + b) * 32 + t] = a;
  }
}

__global__ __launch_bounds__(256) void k_attn(const float* __restrict__ recs,
                                              const float* __restrict__ qw, const float* __restrict__ qb,
                                              const float* __restrict__ kw, const float* __restrict__ kb,
                                              const float* __restrict__ vw, const float* __restrict__ vb,
                                              float* __restrict__ att) {
  int t = threadIdx.x;
  int b = blockIdx.x * 8 + (t >> 5);
  int d = t & 31;
  float x0 = recs[((size_t)0 * BB + b) * 32 + d];
  float x1 = recs[((size_t)1 * BB + b) * 32 + d];
  float x2 = recs[((size_t)2 * BB + b) * 32 + d];
  float q0 = qb[d], q1 = q0, q2 = q0;
  float c0 = kb[d], c1 = c0, c2 = c0;
  float v0 = vb[d], v1 = v0, v2 = v0;
#pragma unroll 4
  for (int kk = 0; kk < 32; ++kk) {
    float xa = __shfl(x0, kk, 32);
    float xb = __shfl(x1, kk, 32);
    float xc = __shfl(x2, kk, 32);
    float wq = qw[kk * 32 + d], wk = kw[kk * 32 + d], wv = vw[kk * 32 + d];
    q0 += xa * wq; q1 += xb * wq; q2 += xc * wq;
    c0 += xa * wk; c1 += xb * wk; c2 += xc * wk;
    v0 += xa * wv; v1 += xb * wv; v2 += xc * wv;
  }
  float qs[3] = {q0, q1, q2}, ks[3] = {c0, c1, c2}, vs[3] = {v0, v1, v2};
  float sc[3][3];
#pragma unroll
  for (int s = 0; s < 3; ++s)
#pragma unroll
    for (int u = 0; u < 3; ++u) {
      float p = qs[s] * ks[u];
#pragma unroll
      for (int off = 16; off; off >>= 1) p += __shfl_xor(p, off, 32);
      sc[s][u] = p * 0.17677669529663687f;  // 1/sqrt(32)
    }
#pragma unroll
  for (int s = 0; s < 3; ++s) {
    float m = fmaxf(sc[s][0], fmaxf(sc[s][1], sc[s][2]));
    float e0 = __expf(sc[s][0] - m), e1 = __expf(sc[s][1] - m), e2 = __expf(sc[s][2] - m);
    float inv = 1.f / (e0 + e1 + e2);
    att[(size_t)b * 96 + s * 32 + d] = (e0 * vs[0] + e1 * vs[1] + e2 * vs[2]) * inv;
  }
}

__global__ __launch_bounds__(256) void k_noise(const float* __restrict__ att_u,
                                               const float* __restrict__ att_i,
                                               uint32_t ku0, uint32_t ku1, uint32_t ki0, uint32_t ki1,
                                               float* __restrict__ n1, float* __restrict__ n2,
                                               float* __restrict__ posdot) {
  int t = threadIdx.x;
  int g = blockIdx.x * 8 + (t >> 5);   // [0, 24576)
  int k = t & 31;
  int side = g / (NLV * BB);
  int rem = g - side * (NLV * BB);
  int l = rem >> 12;
  int b = rem & 4095;
  const float* att = side ? att_i : att_u;
  uint32_t ka = side ? ki0 : ku0;
  uint32_t kb = side ? ki1 : ku1;
  float r = att[(size_t)b * 96 + l * 32 + k];
  float ss = r * r;
#pragma unroll
  for (int off = 16; off; off >>= 1) ss += __shfl_xor(ss, off, 32);
  float v1 = r / fmaxf(sqrtf(ss), 1e-12f);
  uint32_t m = ((uint32_t)(l * BB + b)) * 32u + (uint32_t)k;
  float u = tf_uniform(ka, kb, m);
  float us = u * u;
#pragma unroll
  for (int off = 16; off; off >>= 1) us += __shfl_xor(us, off, 32);
  float un = u / fmaxf(sqrtf(us), 1e-12f);
  float sgn = (r > 0.f) ? 1.f : ((r < 0.f) ? -1.f : 0.f);
  float rn = r + sgn * un * 0.1f;
  float s2 = rn * rn;
#pragma unroll
  for (int off = 16; off; off >>= 1) s2 += __shfl_xor(s2, off, 32);
  float v2 = rn / fmaxf(sqrtf(s2), 1e-12f);
  float pd = v1 * v2;
#pragma unroll
  for (int off = 16; off; off >>= 1) pd += __shfl_xor(pd, off, 32);
  size_t o = (size_t)g * 32 + k;
  n1[o] = v1;
  n2[o] = v2;
  if (k == 0) posdot[g] = pd;
}

// ttl: per-slice [4096 x 4096] exp(dot/tau) row-sums, float4 everywhere.
// grid (16, 8, 6): each block covers 256 i's x 512 j's (4 staged chunks of 128).
__global__ __launch_bounds__(256) void k_ttl(const float* __restrict__ n1,
                                             const float* __restrict__ n2,
                                             float* __restrict__ ttl) {
  __shared__ float4 sj[128][8];
  int sl = blockIdx.z;
  int t = threadIdx.x;
  int i = blockIdx.x * 256 + t;
  const float* n1b = n1 + (size_t)sl * BB * 32;
  const float* n2b = n2 + (size_t)sl * BB * 32;
  float4 r[8];
#pragma unroll
  for (int k = 0; k < 8; ++k) r[k] = *(const float4*)&n1b[(size_t)i * 32 + k * 4];
  float acc = 0.f;
  for (int jc = 0; jc < 4; ++jc) {
    int j0 = blockIdx.y * 512 + jc * 128;
    __syncthreads();
    for (int idx = t; idx < 128 * 8; idx += 256) {
      int jj = idx >> 3, kk = idx & 7;
      sj[jj][kk] = *(const float4*)&n2b[(size_t)(j0 + jj) * 32 + kk * 4];
    }
    __syncthreads();
    for (int j = 0; j < 128; ++j) {
      float d0 = 0.f, d1 = 0.f, d2 = 0.f, d3 = 0.f;
#pragma unroll
      for (int k = 0; k < 8; ++k) {
        float4 sv = sj[j][k];
        d0 = fmaf(r[k].x, sv.x, d0);
        d1 = fmaf(r[k].y, sv.y, d1);
        d2 = fmaf(r[k].z, sv.z, d2);
        d3 = fmaf(r[k].w, sv.w, d3);
      }
      acc += __expf(((d0 + d1) + (d2 + d3)) * 5.0f);  // 1/TAU = 5
    }
  }
  atomicAdd(&ttl[sl * BB + i], acc);
}

__global__ __launch_bounds__(1024) void k_clred(const float* __restrict__ ttl,
                                                const float* __restrict__ posdot,
                                                float* __restrict__ outp) {
  __shared__ float red[1024];
  int t = threadIdx.x;
  float a = 0.f;
  for (int idx = t; idx < 6 * BB; idx += 1024)
    a += logf(ttl[idx]) - posdot[idx] * 5.0f;
  red[t] = a;
  __syncthreads();
  for (int off = 512; off; off >>= 1) {
    if (t < off) red[t] += red[t + off];
    __syncthreads();
  }
  if (t == 0) outp[2 * BB] = red[0] * (1.f / 12288.f);  // (cl_u + cl_i)
}

__global__ __launch_bounds__(256) void k_head(const float* __restrict__ att_u,
                                              const float* __restrict__ att_i,
                                              const float* __restrict__ skills,
                                              const float* __restrict__ w1, const float* __restrict__ b1,
                                              const float* __restrict__ w2, const float* __restrict__ b2,
                                              const float* __restrict__ pw, const float* __restrict__ pb,
                                              float* __restrict__ outp) {
  __shared__ float diag[4][96], t1[4][64];
  int t = threadIdx.x;
  int w = t >> 6, lane = t & 63;
  int b = blockIdx.x * 4 + w;
  for (int j = lane; j < 96; j += 64) {
    float su = 1.f / (1.f + __expf(-att_u[(size_t)b * 96 + j]));
    float si = 1.f / (1.f + __expf(-att_i[(size_t)b * 96 + j]));
    diag[w][j] = (su - si) * skills[(size_t)b * 96 + j];
  }
  __syncthreads();
  float a = b1[lane];
#pragma unroll 8
  for (int j = 0; j < 96; ++j) a += diag[w][j] * w1[j * 64 + lane];
  t1[w][lane] = tanhf(a);
  __syncthreads();
  float h = b2[lane];
#pragma unroll 8
  for (int kk = 0; kk < 64; ++kk) h += t1[w][kk] * w2[kk * 64 + lane];
  float p0 = h * pw[lane * 2 + 0];
  float p1 = h * pw[lane * 2 + 1];
#pragma unroll
  for (int off = 32; off; off >>= 1) {
    p0 += __shfl_xor(p0, off, 64);
    p1 += __shfl_xor(p1, off, 64);
  }
  if (lane == 0) {
    float l0 = p0 + pb[0], l1 = p1 + pb[1];
    float m = fmaxf(l0, l1);
    float e0 = __expf(l0 - m), e1 = __expf(l1 - m);
    float inv = 1.f / (e0 + e1);
    outp[(size_t)b * 2 + 0] = e0 * inv;
    outp[(size_t)b * 2 + 1] = e1 * inv;
  }
}

// ---------------- launcher ----------------
extern "C" void kernel_launch(void* const* d_in, const int* in_sizes, int n_in,
                              void* d_out, int out_size, void* d_ws, size_t ws_size,
                              hipStream_t stream) {
  const float* ego    = (const float*)d_in[0];
  const float* gc_w   = (const float*)d_in[1];
  const float* gc_b   = (const float*)d_in[2];
  const float* bi_w   = (const float*)d_in[3];
  const float* bi_b   = (const float*)d_in[4];
  const float* uh_w   = (const float*)d_in[5];
  const float* uh_b   = (const float*)d_in[6];
  const float* ih_w   = (const float*)d_in[7];
  const float* ih_b   = (const float*)d_in[8];
  const float* ud_w1  = (const float*)d_in[9];
  const float* ud_b1  = (const float*)d_in[10];
  const float* ud_w2  = (const float*)d_in[11];
  const float* ud_b2  = (const float*)d_in[12];
  const float* id_w1  = (const float*)d_in[13];
  const float* id_b1  = (const float*)d_in[14];
  const float* id_w2  = (const float*)d_in[15];
  const float* id_b2  = (const float*)d_in[16];
  const float* q_w    = (const float*)d_in[17];
  const float* q_b    = (const float*)d_in[18];
  const float* k_w    = (const float*)d_in[19];
  const float* k_b    = (const float*)d_in[20];
  const float* v_w    = (const float*)d_in[21];
  const float* v_b    = (const float*)d_in[22];
  const float* dg_w1  = (const float*)d_in[23];
  const float* dg_b1  = (const float*)d_in[24];
  const float* dg_w2  = (const float*)d_in[25];
  const float* dg_b2  = (const float*)d_in[26];
  const float* pr_w   = (const float*)d_in[27];
  const float* pr_b   = (const float*)d_in[28];
  const float* adj_vals = (const float*)d_in[29];
  const float* skills = (const float*)d_in[30];
  const int* user_id  = (const int*)d_in[31];
  const int* item_id  = (const int*)d_in[32];
  const int* adj_rows = (const int*)d_in[33];
  const int* adj_cols = (const int*)d_in[34];
  float* outp = (float*)d_out;

  char* w = (char*)d_ws;
  auto alloc = [&](size_t bytes) -> char* {
    char* p = w;
    w += (bytes + 255) & ~(size_t)255;
    return p;
  };
  float* E      = (float*)alloc((size_t)NODE_N * DD * 4);
  float* Esum   = (float*)alloc((size_t)NODE_N * DD * 4);
  float* side   = (float*)alloc((size_t)NODE_N * DD * 4);
  float* svals  = (float*)alloc((size_t)NNZE * 4);
  int*   scols  = (int*)  alloc((size_t)NNZE * 4);
  int*   counts = (int*)  alloc((size_t)NODE_N * 4);
  int*   row_start = (int*)alloc((size_t)(NODE_N + 1) * 4);
  int*   cursor = (int*)  alloc((size_t)(NODE_N + 1) * 4);
  int*   bsums  = (int*)  alloc(256 * 4);
  float* ue     = (float*)alloc((size_t)BB * 64 * 4);
  float* ie     = (float*)alloc((size_t)BB * 64 * 4);
  float* recs_u = (float*)alloc((size_t)NLV * BB * 32 * 4);
  float* recs_i = (float*)alloc((size_t)NLV * BB * 32 * 4);
  float* att_u  = (float*)alloc((size_t)BB * 96 * 4);
  float* att_i  = (float*)alloc((size_t)BB * 96 * 4);
  float* n1     = (float*)alloc((size_t)6 * BB * 32 * 4);
  float* n2     = (float*)alloc((size_t)6 * BB * 32 * 4);
  float* posdot = (float*)alloc((size_t)6 * BB * 4);
  float* ttl    = (float*)alloc((size_t)6 * BB * 4);

  // host-side: kc = jax.random.split(jax.random.key(42), 2)
  uint32_t a0 = 0, a1 = 2, b0 = 1, b1 = 3;
  tf_block(0u, 42u, a0, a1);
  tf_block(0u, 42u, b0, b1);
  uint32_t ku0 = a0, ku1 = b0;   // kc[0] -> u side
  uint32_t ki0 = a1, ki1 = b1;   // kc[1] -> i side

  hipMemsetAsync(counts, 0, (size_t)NODE_N * 4, stream);
  hipMemsetAsync(ttl, 0, (size_t)6 * BB * 4, stream);

  k_init<<<37500, 256, 0, stream>>>(ego, E, Esum);
  k_hist<<<9375, 256, 0, stream>>>(adj_rows, counts);
  k_scan1<<<147, 1024, 0, stream>>>(counts, row_start + 1, bsums);
  k_scan2<<<1, 256, 0, stream>>>(bsums, 147);
  k_scan3<<<147, 1024, 0, stream>>>(row_start, cursor, bsums);
  k_scatter<<<9375, 256, 0, stream>>>(adj_rows, adj_cols, adj_vals, cursor, svals, scols);

  for (int l = 0; l < 2; ++l) {
    k_spmm<<<37500, 256, 0, stream>>>(E, svals, scols, row_start, side);
    k_transform<<<TR_GRID, 256, 0, stream>>>(gc_w + l * 4096, gc_b + l * 64,
                                             bi_w + l * 4096, bi_b + l * 64,
                                             E, Esum, side);
  }

  k_gather<<<4096, 128, 0, stream>>>(Esum, user_id, item_id, ue, ie);

  dim3 ge(4096, 3);
  k_encoder<<<ge, 256, 0, stream>>>(ue, uh_w, uh_b, ud_w1, ud_b1, ud_w2, ud_b2, recs_u);
  k_encoder<<<ge, 256, 0, stream>>>(ie, ih_w, ih_b, id_w1, id_b1, id_w2, id_b2, recs_i);

  k_attn<<<512, 256, 0, stream>>>(recs_u, q_w, q_b, k_w, k_b, v_w, v_b, att_u);
  k_attn<<<512, 256, 0, stream>>>(recs_i, q_w, q_b, k_w, k_b, v_w, v_b, att_i);

  k_noise<<<3072, 256, 0, stream>>>(att_u, att_i, ku0, ku1, ki0, ki1, n1, n2, posdot);

  dim3 gt(16, 8, 6);
  k_ttl<<<gt, 256, 0, stream>>>(n1, n2, ttl);
  k_clred<<<1, 1024, 0, stream>>>(ttl, posdot, outp);

  k_head<<<1024, 256, 0, stream>>>(att_u, att_i, skills, dg_w1, dg_b1, dg_w2, dg_b2,
                                   pr_w, pr_b, outp);
}

// Round 3
// 1126.316 us; speedup vs baseline: 1.2909x; 1.0418x over previous
//
#include <hip/hip_runtime.h>
#include <stdint.h>
#include <math.h>

#define USER_N 100000
#define NODE_N 150000
#define DD 64
#define NNZE 2400000
#define BB 4096
#define NLV 3
#define LF 32
#define HALF_SZ 196608u  /* (3*4096*32)/2 */

// ---------------- threefry2x32 (JAX original mode) ----------------
__host__ __device__ inline void tf_block(uint32_t k0, uint32_t k1, uint32_t& x0, uint32_t& x1) {
  uint32_t ks[3] = {k0, k1, k0 ^ k1 ^ 0x1BD11BDAu};
  x0 += ks[0]; x1 += ks[1];
  const int R0[4] = {13, 15, 26, 6};
  const int R1[4] = {17, 29, 16, 24};
#pragma unroll
  for (int i = 0; i < 5; ++i) {
    const int* R = (i & 1) ? R1 : R0;
#pragma unroll
    for (int j = 0; j < 4; ++j) {
      x0 += x1;
      x1 = (x1 << R[j]) | (x1 >> (32 - R[j]));
      x1 ^= x0;
    }
    x0 += ks[(i + 1) % 3];
    x1 += ks[(i + 2) % 3] + (uint32_t)(i + 1);
  }
}

__device__ inline float tf_uniform(uint32_t ka, uint32_t kb, uint32_t m) {
  uint32_t x0, x1;
  bool first = m < HALF_SZ;
  if (first) { x0 = m; x1 = m + HALF_SZ; } else { x0 = m - HALF_SZ; x1 = m; }
  tf_block(ka, kb, x0, x1);
  uint32_t bits = first ? x0 : x1;
  return __uint_as_float((bits >> 9) | 0x3f800000u) - 1.0f;
}

// ---------------- kernels ----------------
__global__ __launch_bounds__(256) void k_init(const float* __restrict__ ego,
                                              float* __restrict__ E, float* __restrict__ Esum) {
  int i = blockIdx.x * 256 + threadIdx.x;  // float4 index
  float4 v = ((const float4*)ego)[i];
  ((float4*)E)[i] = v;
  ((float4*)Esum)[i] = v;
}

__global__ __launch_bounds__(256) void k_hist(const int* __restrict__ rows, int* __restrict__ counts) {
  int e = blockIdx.x * 256 + threadIdx.x;
  if (e < NNZE) atomicAdd(&counts[rows[e]], 1);
}

__global__ __launch_bounds__(1024) void k_scan1(const int* __restrict__ counts,
                                                int* __restrict__ rs1, int* __restrict__ bsums) {
  __shared__ int buf[1024];
  int t = threadIdx.x;
  int i = blockIdx.x * 1024 + t;
  int v = (i < NODE_N) ? counts[i] : 0;
  buf[t] = v;
  __syncthreads();
  for (int off = 1; off < 1024; off <<= 1) {
    int add = (t >= off) ? buf[t - off] : 0;
    __syncthreads();
    buf[t] += add;
    __syncthreads();
  }
  if (i < NODE_N) rs1[i] = buf[t];
  if (t == 1023) bsums[blockIdx.x] = buf[1023];
}

__global__ __launch_bounds__(256) void k_scan2(int* __restrict__ bsums, int nb) {
  __shared__ int buf[256];
  int t = threadIdx.x;
  int v = (t < nb) ? bsums[t] : 0;
  buf[t] = v;
  __syncthreads();
  for (int off = 1; off < 256; off <<= 1) {
    int add = (t >= off) ? buf[t - off] : 0;
    __syncthreads();
    buf[t] += add;
    __syncthreads();
  }
  if (t < nb) bsums[t] = buf[t] - v;  // exclusive
}

__global__ __launch_bounds__(1024) void k_scan3(int* __restrict__ row_start,
                                                int* __restrict__ cursor,
                                                const int* __restrict__ bsums) {
  int i = blockIdx.x * 1024 + threadIdx.x;
  if (i < NODE_N) {
    int v = row_start[i + 1] + bsums[blockIdx.x];
    row_start[i + 1] = v;
    cursor[i + 1] = v;
  }
  if (i == 0) { row_start[0] = 0; cursor[0] = 0; }
}

// CSR scatter with packed {col, val} 8B records: one store per edge.
__global__ __launch_bounds__(256) void k_scatter(const int* __restrict__ rows,
                                                 const int* __restrict__ cols,
                                                 const float* __restrict__ vals,
                                                 int* __restrict__ cursor,
                                                 uint2* __restrict__ sedge) {
  int e = blockIdx.x * 256 + threadIdx.x;
  if (e < NNZE) {
    int r = rows[e];
    int p = atomicAdd(&cursor[r], 1);
    sedge[p] = make_uint2((uint32_t)cols[e], __float_as_uint(vals[e]));
  }
}

// wave-per-row SpMM: 4 edges per iteration via 16-lane float4 gathers.
// subgroup g = lane>>4 picks the edge, slot q = lane&15 picks 4 of 64 dims.
__global__ __launch_bounds__(256) void k_spmm(const float* __restrict__ E,
                                              const uint2* __restrict__ sedge,
                                              const int* __restrict__ row_start,
                                              float* __restrict__ side) {
  int r = blockIdx.x * 4 + (threadIdx.x >> 6);
  int lane = threadIdx.x & 63;
  int g = lane >> 4;
  int q = lane & 15;
  int rs = row_start[r], re = row_start[r + 1];
  float4 acc = make_float4(0.f, 0.f, 0.f, 0.f);
  int e = rs;
  for (; e + 8 <= re; e += 8) {
    uint2 e0 = sedge[e + g];
    uint2 e1 = sedge[e + 4 + g];
    float4 a0 = *(const float4*)&E[(size_t)e0.x * DD + q * 4];
    float4 a1 = *(const float4*)&E[(size_t)e1.x * DD + q * 4];
    float v0 = __uint_as_float(e0.y);
    float v1 = __uint_as_float(e1.y);
    acc.x = fmaf(v0, a0.x, acc.x);
    acc.y = fmaf(v0, a0.y, acc.y);
    acc.z = fmaf(v0, a0.z, acc.z);
    acc.w = fmaf(v0, a0.w, acc.w);
    acc.x = fmaf(v1, a1.x, acc.x);
    acc.y = fmaf(v1, a1.y, acc.y);
    acc.z = fmaf(v1, a1.z, acc.z);
    acc.w = fmaf(v1, a1.w, acc.w);
  }
  for (; e + 4 <= re; e += 4) {
    uint2 e0 = sedge[e + g];
    float4 a0 = *(const float4*)&E[(size_t)e0.x * DD + q * 4];
    float v0 = __uint_as_float(e0.y);
    acc.x = fmaf(v0, a0.x, acc.x);
    acc.y = fmaf(v0, a0.y, acc.y);
    acc.z = fmaf(v0, a0.z, acc.z);
    acc.w = fmaf(v0, a0.w, acc.w);
  }
  for (; e < re; ++e) {
    if (g == ((e - rs) & 3)) {
      uint2 e0 = sedge[e];
      float4 a0 = *(const float4*)&E[(size_t)e0.x * DD + q * 4];
      float v0 = __uint_as_float(e0.y);
      acc.x = fmaf(v0, a0.x, acc.x);
      acc.y = fmaf(v0, a0.y, acc.y);
      acc.z = fmaf(v0, a0.z, acc.z);
      acc.w = fmaf(v0, a0.w, acc.w);
    }
  }
  // sum the 4 subgroup partials (lane bits 4,5)
#pragma unroll
  for (int off = 16; off <= 32; off <<= 1) {
    acc.x += __shfl_xor(acc.x, off, 64);
    acc.y += __shfl_xor(acc.y, off, 64);
    acc.z += __shfl_xor(acc.z, off, 64);
    acc.w += __shfl_xor(acc.w, off, 64);
  }
  if (g == 0) *(float4*)&side[(size_t)r * DD + q * 4] = acc;
}

// Transform: weights held in VGPR columns, row vectors broadcast from LDS via b128.
#define TR_ROWS 16
#define TR_GRID 1875   /* 9375 chunks / 5 per block */
__global__ __launch_bounds__(256) void k_transform(const float* __restrict__ gw,
                                                   const float* __restrict__ gb,
                                                   const float* __restrict__ bw,
                                                   const float* __restrict__ bb,
                                                   float* __restrict__ E, float* __restrict__ Esum,
                                                   const float* __restrict__ side) {
  __shared__ float ss[TR_ROWS][64];
  __shared__ float pp[TR_ROWS][64];
  int t = threadIdx.x;
  int lane = t & 63;
  int wv = t >> 6;
  float wgr[64], wbr[64];
#pragma unroll
  for (int k = 0; k < 64; ++k) {
    wgr[k] = gw[k * 64 + lane];
    wbr[k] = bw[k * 64 + lane];
  }
  float gbl = gb[lane], bbl = bb[lane];
  const int nchunks = NODE_N / TR_ROWS;  // 9375
  for (int chunk = blockIdx.x; chunk < nchunks; chunk += TR_GRID) {
    int r0 = chunk * TR_ROWS;
    {
      int row = t >> 4;
      int col = (t & 15) * 4;
      float4 sv = *(const float4*)&side[(size_t)(r0 + row) * 64 + col];
      float4 ev = *(const float4*)&E[(size_t)(r0 + row) * 64 + col];
      *(float4*)&ss[row][col] = sv;
      pp[row][col + 0] = sv.x * ev.x;
      pp[row][col + 1] = sv.y * ev.y;
      pp[row][col + 2] = sv.z * ev.z;
      pp[row][col + 3] = sv.w * ev.w;
    }
    __syncthreads();
#pragma unroll
    for (int rr = 0; rr < 4; ++rr) {
      int row = wv + rr * 4;
      float a10 = 0.f, a11 = 0.f, a12 = 0.f, a13 = 0.f;
      float a20 = 0.f, a21 = 0.f, a22 = 0.f, a23 = 0.f;
#pragma unroll
      for (int k = 0; k < 64; k += 4) {
        float4 s4 = *(const float4*)&ss[row][k];
        float4 p4 = *(const float4*)&pp[row][k];
        a10 = fmaf(s4.x, wgr[k + 0], a10);
        a11 = fmaf(s4.y, wgr[k + 1], a11);
        a12 = fmaf(s4.z, wgr[k + 2], a12);
        a13 = fmaf(s4.w, wgr[k + 3], a13);
        a20 = fmaf(p4.x, wbr[k + 0], a20);
        a21 = fmaf(p4.y, wbr[k + 1], a21);
        a22 = fmaf(p4.z, wbr[k + 2], a22);
        a23 = fmaf(p4.w, wbr[k + 3], a23);
      }
      float a1 = gbl + ((a10 + a11) + (a12 + a13));
      float a2 = bbl + ((a20 + a21) + (a22 + a23));
      a1 = (a1 > 0.f) ? a1 : 0.01f * a1;
      a2 = (a2 > 0.f) ? a2 : 0.01f * a2;
      float v = a1 + a2;
      float sq = v * v;
#pragma unroll
      for (int off = 32; off; off >>= 1) sq += __shfl_xor(sq, off, 64);
      v = v / fmaxf(sqrtf(sq), 1e-12f);
      size_t o = (size_t)(r0 + row) * 64 + lane;
      E[o] = v;
      Esum[o] += v;
    }
    __syncthreads();
  }
}

__global__ __launch_bounds__(128) void k_gather(const float* __restrict__ Esum,
                                                const int* __restrict__ uid,
                                                const int* __restrict__ iid,
                                                float* __restrict__ ue, float* __restrict__ ie) {
  int b = blockIdx.x, t = threadIdx.x;
  if (t < 64) ue[(size_t)b * 64 + t] = Esum[(size_t)uid[b] * 64 + t];
  else {
    int d = t - 64;
    ie[(size_t)b * 64 + d] = Esum[(size_t)(USER_N + iid[b]) * 64 + d];
  }
}

__global__ __launch_bounds__(256) void k_encoder(const float* __restrict__ xin,
                                                 const float* __restrict__ hw, const float* __restrict__ hb,
                                                 const float* __restrict__ w1, const float* __restrict__ b1,
                                                 const float* __restrict__ w2, const float* __restrict__ b2,
                                                 float* __restrict__ recs) {
  __shared__ float sx[64], sreps[64], st[256];
  int b = blockIdx.x, l = blockIdx.y, t = threadIdx.x;
  if (t < 64) sx[t] = xin[(size_t)b * 64 + t];
  __syncthreads();
  if (t < 64) {
    const float* W = hw + l * 64 * 64;
    float a = hb[l * 64 + t];
#pragma unroll 8
    for (int k = 0; k < 64; ++k) a += sx[k] * W[k * 64 + t];
    sreps[t] = tanhf(a);
  }
  __syncthreads();
  {
    const float* W = w1 + l * 64 * 256;
    float a = b1[l * 256 + t];
#pragma unroll 8
    for (int k = 0; k < 64; ++k) a += sreps[k] * W[k * 256 + t];
    st[t] = tanhf(a);
  }
  __syncthreads();
  if (t < 32) {
    const float* W = w2 + l * 256 * 32;
    float a = b2[l * 32 + t];
#pragma unroll 8
    for (int k = 0; k < 256; ++k) a += st[k] * W[k * 32 + t];
    recs[((size_t)l * BB + b) * 32 + t] = a;
  }
}

__global__ __launch_bounds__(256) void k_attn(const float* __restrict__ recs,
                                              const float* __restrict__ qw, const float* __restrict__ qb,
                                              const float* __restrict__ kw, const float* __restrict__ kb,
                                              const float* __restrict__ vw, const float* __restrict__ vb,
                                              float* __restrict__ att) {
  int t = threadIdx.x;
  int b = blockIdx.x * 8 + (t >> 5);
  int d = t & 31;
  float x0 = recs[((size_t)0 * BB + b) * 32 + d];
  float x1 = recs[((size_t)1 * BB + b) * 32 + d];
  float x2 = recs[((size_t)2 * BB + b) * 32 + d];
  float q0 = qb[d], q1 = q0, q2 = q0;
  float c0 = kb[d], c1 = c0, c2 = c0;
  float v0 = vb[d], v1 = v0, v2 = v0;
#pragma unroll 4
  for (int kk = 0; kk < 32; ++kk) {
    float xa = __shfl(x0, kk, 32);
    float xb = __shfl(x1, kk, 32);
    float xc = __shfl(x2, kk, 32);
    float wq = qw[kk * 32 + d], wk = kw[kk * 32 + d], wv = vw[kk * 32 + d];
    q0 += xa * wq; q1 += xb * wq; q2 += xc * wq;
    c0 += xa * wk; c1 += xb * wk; c2 += xc * wk;
    v0 += xa * wv; v1 += xb * wv; v2 += xc * wv;
  }
  float qs[3] = {q0, q1, q2}, ks[3] = {c0, c1, c2}, vs[3] = {v0, v1, v2};
  float sc[3][3];
#pragma unroll
  for (int s = 0; s < 3; ++s)
#pragma unroll
    for (int u = 0; u < 3; ++u) {
      float p = qs[s] * ks[u];
#pragma unroll
      for (int off = 16; off; off >>= 1) p += __shfl_xor(p, off, 32);
      sc[s][u] = p * 0.17677669529663687f;  // 1/sqrt(32)
    }
#pragma unroll
  for (int s = 0; s < 3; ++s) {
    float m = fmaxf(sc[s][0], fmaxf(sc[s][1], sc[s][2]));
    float e0 = __expf(sc[s][0] - m), e1 = __expf(sc[s][1] - m), e2 = __expf(sc[s][2] - m);
    float inv = 1.f / (e0 + e1 + e2);
    att[(size_t)b * 96 + s * 32 + d] = (e0 * vs[0] + e1 * vs[1] + e2 * vs[2]) * inv;
  }
}

__global__ __launch_bounds__(256) void k_noise(const float* __restrict__ att_u,
                                               const float* __restrict__ att_i,
                                               uint32_t ku0, uint32_t ku1, uint32_t ki0, uint32_t ki1,
                                               float* __restrict__ n1, float* __restrict__ n2,
                                               float* __restrict__ posdot) {
  int t = threadIdx.x;
  int g = blockIdx.x * 8 + (t >> 5);   // [0, 24576)
  int k = t & 31;
  int side = g / (NLV * BB);
  int rem = g - side * (NLV * BB);
  int l = rem >> 12;
  int b = rem & 4095;
  const float* att = side ? att_i : att_u;
  uint32_t ka = side ? ki0 : ku0;
  uint32_t kb = side ? ki1 : ku1;
  float r = att[(size_t)b * 96 + l * 32 + k];
  float ss = r * r;
#pragma unroll
  for (int off = 16; off; off >>= 1) ss += __shfl_xor(ss, off, 32);
  float v1 = r / fmaxf(sqrtf(ss), 1e-12f);
  uint32_t m = ((uint32_t)(l * BB + b)) * 32u + (uint32_t)k;
  float u = tf_uniform(ka, kb, m);
  float us = u * u;
#pragma unroll
  for (int off = 16; off; off >>= 1) us += __shfl_xor(us, off, 32);
  float un = u / fmaxf(sqrtf(us), 1e-12f);
  float sgn = (r > 0.f) ? 1.f : ((r < 0.f) ? -1.f : 0.f);
  float rn = r + sgn * un * 0.1f;
  float s2 = rn * rn;
#pragma unroll
  for (int off = 16; off; off >>= 1) s2 += __shfl_xor(s2, off, 32);
  float v2 = rn / fmaxf(sqrtf(s2), 1e-12f);
  float pd = v1 * v2;
#pragma unroll
  for (int off = 16; off; off >>= 1) pd += __shfl_xor(pd, off, 32);
  size_t o = (size_t)g * 32 + k;
  n1[o] = v1;
  n2[o] = v2;
  if (k == 0) posdot[g] = pd;
}

// ttl: per-slice [4096 x 4096] exp(dot/tau) row-sums.
// 2 i-rows per thread share each staged j-chunk read: 8 LDS reads serve 64 FMAs.
// grid (8, 16, 6): block = 512 i's x 256 j's (2 staged chunks of 128).
__global__ __launch_bounds__(256) void k_ttl(const float* __restrict__ n1,
                                             const float* __restrict__ n2,
                                             float* __restrict__ ttl) {
  __shared__ float4 sj[128][8];
  int sl = blockIdx.z;
  int t = threadIdx.x;
  int ia = blockIdx.x * 512 + t;
  int ib = ia + 256;
  const float* n1b = n1 + (size_t)sl * BB * 32;
  const float* n2b = n2 + (size_t)sl * BB * 32;
  float4 ra[8], rb[8];
#pragma unroll
  for (int k = 0; k < 8; ++k) {
    ra[k] = *(const float4*)&n1b[(size_t)ia * 32 + k * 4];
    rb[k] = *(const float4*)&n1b[(size_t)ib * 32 + k * 4];
  }
  float acca = 0.f, accb = 0.f;
  for (int jc = 0; jc < 2; ++jc) {
    int j0 = blockIdx.y * 256 + jc * 128;
    __syncthreads();
    for (int idx = t; idx < 128 * 8; idx += 256) {
      int jj = idx >> 3, kk = idx & 7;
      sj[jj][kk] = *(const float4*)&n2b[(size_t)(j0 + jj) * 32 + kk * 4];
    }
    __syncthreads();
    for (int j = 0; j < 128; ++j) {
      float a0 = 0.f, a1 = 0.f, a2 = 0.f, a3 = 0.f;
      float b0 = 0.f, b1 = 0.f, b2 = 0.f, b3 = 0.f;
#pragma unroll
      for (int k = 0; k < 8; ++k) {
        float4 sv = sj[j][k];
        a0 = fmaf(ra[k].x, sv.x, a0);
        a1 = fmaf(ra[k].y, sv.y, a1);
        a2 = fmaf(ra[k].z, sv.z, a2);
        a3 = fmaf(ra[k].w, sv.w, a3);
        b0 = fmaf(rb[k].x, sv.x, b0);
        b1 = fmaf(rb[k].y, sv.y, b1);
        b2 = fmaf(rb[k].z, sv.z, b2);
        b3 = fmaf(rb[k].w, sv.w, b3);
      }
      acca += __expf(((a0 + a1) + (a2 + a3)) * 5.0f);  // 1/TAU = 5
      accb += __expf(((b0 + b1) + (b2 + b3)) * 5.0f);
    }
  }
  atomicAdd(&ttl[sl * BB + ia], acca);
  atomicAdd(&ttl[sl * BB + ib], accb);
}

__global__ __launch_bounds__(1024) void k_clred(const float* __restrict__ ttl,
                                                const float* __restrict__ posdot,
                                                float* __restrict__ outp) {
  __shared__ float red[1024];
  int t = threadIdx.x;
  float a = 0.f;
  for (int idx = t; idx < 6 * BB; idx += 1024)
    a += logf(ttl[idx]) - posdot[idx] * 5.0f;
  red[t] = a;
  __syncthreads();
  for (int off = 512; off; off >>= 1) {
    if (t < off) red[t] += red[t + off];
    __syncthreads();
  }
  if (t == 0) outp[2 * BB] = red[0] * (1.f / 12288.f);  // (cl_u + cl_i)
}

__global__ __launch_bounds__(256) void k_head(const float* __restrict__ att_u,
                                              const float* __restrict__ att_i,
                                              const float* __restrict__ skills,
                                              const float* __restrict__ w1, const float* __restrict__ b1,
                                              const float* __restrict__ w2, const float* __restrict__ b2,
                                              const float* __restrict__ pw, const float* __restrict__ pb,
                                              float* __restrict__ outp) {
  __shared__ float diag[4][96], t1[4][64];
  int t = threadIdx.x;
  int w = t >> 6, lane = t & 63;
  int b = blockIdx.x * 4 + w;
  for (int j = lane; j < 96; j += 64) {
    float su = 1.f / (1.f + __expf(-att_u[(size_t)b * 96 + j]));
    float si = 1.f / (1.f + __expf(-att_i[(size_t)b * 96 + j]));
    diag[w][j] = (su - si) * skills[(size_t)b * 96 + j];
  }
  __syncthreads();
  float a = b1[lane];
#pragma unroll 8
  for (int j = 0; j < 96; ++j) a += diag[w][j] * w1[j * 64 + lane];
  t1[w][lane] = tanhf(a);
  __syncthreads();
  float h = b2[lane];
#pragma unroll 8
  for (int kk = 0; kk < 64; ++kk) h += t1[w][kk] * w2[kk * 64 + lane];
  float p0 = h * pw[lane * 2 + 0];
  float p1 = h * pw[lane * 2 + 1];
#pragma unroll
  for (int off = 32; off; off >>= 1) {
    p0 += __shfl_xor(p0, off, 64);
    p1 += __shfl_xor(p1, off, 64);
  }
  if (lane == 0) {
    float l0 = p0 + pb[0], l1 = p1 + pb[1];
    float m = fmaxf(l0, l1);
    float e0 = __expf(l0 - m), e1 = __expf(l1 - m);
    float inv = 1.f / (e0 + e1);
    outp[(size_t)b * 2 + 0] = e0 * inv;
    outp[(size_t)b * 2 + 1] = e1 * inv;
  }
}

// ---------------- launcher ----------------
extern "C" void kernel_launch(void* const* d_in, const int* in_sizes, int n_in,
                              void* d_out, int out_size, void* d_ws, size_t ws_size,
                              hipStream_t stream) {
  const float* ego    = (const float*)d_in[0];
  const float* gc_w   = (const float*)d_in[1];
  const float* gc_b   = (const float*)d_in[2];
  const float* bi_w   = (const float*)d_in[3];
  const float* bi_b   = (const float*)d_in[4];
  const float* uh_w   = (const float*)d_in[5];
  const float* uh_b   = (const float*)d_in[6];
  const float* ih_w   = (const float*)d_in[7];
  const float* ih_b   = (const float*)d_in[8];
  const float* ud_w1  = (const float*)d_in[9];
  const float* ud_b1  = (const float*)d_in[10];
  const float* ud_w2  = (const float*)d_in[11];
  const float* ud_b2  = (const float*)d_in[12];
  const float* id_w1  = (const float*)d_in[13];
  const float* id_b1  = (const float*)d_in[14];
  const float* id_w2  = (const float*)d_in[15];
  const float* id_b2  = (const float*)d_in[16];
  const float* q_w    = (const float*)d_in[17];
  const float* q_b    = (const float*)d_in[18];
  const float* k_w    = (const float*)d_in[19];
  const float* k_b    = (const float*)d_in[20];
  const float* v_w    = (const float*)d_in[21];
  const float* v_b    = (const float*)d_in[22];
  const float* dg_w1  = (const float*)d_in[23];
  const float* dg_b1  = (const float*)d_in[24];
  const float* dg_w2  = (const float*)d_in[25];
  const float* dg_b2  = (const float*)d_in[26];
  const float* pr_w   = (const float*)d_in[27];
  const float* pr_b   = (const float*)d_in[28];
  const float* adj_vals = (const float*)d_in[29];
  const float* skills = (const float*)d_in[30];
  const int* user_id  = (const int*)d_in[31];
  const int* item_id  = (const int*)d_in[32];
  const int* adj_rows = (const int*)d_in[33];
  const int* adj_cols = (const int*)d_in[34];
  float* outp = (float*)d_out;

  char* w = (char*)d_ws;
  auto alloc = [&](size_t bytes) -> char* {
    char* p = w;
    w += (bytes + 255) & ~(size_t)255;
    return p;
  };
  float* E      = (float*)alloc((size_t)NODE_N * DD * 4);
  float* Esum   = (float*)alloc((size_t)NODE_N * DD * 4);
  float* side   = (float*)alloc((size_t)NODE_N * DD * 4);
  uint2* sedge  = (uint2*)alloc((size_t)NNZE * 8);
  int*   counts = (int*)  alloc((size_t)NODE_N * 4);
  int*   row_start = (int*)alloc((size_t)(NODE_N + 1) * 4);
  int*   cursor = (int*)  alloc((size_t)(NODE_N + 1) * 4);
  int*   bsums  = (int*)  alloc(256 * 4);
  float* ue     = (float*)alloc((size_t)BB * 64 * 4);
  float* ie     = (float*)alloc((size_t)BB * 64 * 4);
  float* recs_u = (float*)alloc((size_t)NLV * BB * 32 * 4);
  float* recs_i = (float*)alloc((size_t)NLV * BB * 32 * 4);
  float* att_u  = (float*)alloc((size_t)BB * 96 * 4);
  float* att_i  = (float*)alloc((size_t)BB * 96 * 4);
  float* n1     = (float*)alloc((size_t)6 * BB * 32 * 4);
  float* n2     = (float*)alloc((size_t)6 * BB * 32 * 4);
  float* posdot = (float*)alloc((size_t)6 * BB * 4);
  float* ttl    = (float*)alloc((size_t)6 * BB * 4);

  // host-side: kc = jax.random.split(jax.random.key(42), 2)
  uint32_t a0 = 0, a1 = 2, b0 = 1, b1 = 3;
  tf_block(0u, 42u, a0, a1);
  tf_block(0u, 42u, b0, b1);
  uint32_t ku0 = a0, ku1 = b0;   // kc[0] -> u side
  uint32_t ki0 = a1, ki1 = b1;   // kc[1] -> i side

  hipMemsetAsync(counts, 0, (size_t)NODE_N * 4, stream);
  hipMemsetAsync(ttl, 0, (size_t)6 * BB * 4, stream);

  k_init<<<9375, 256, 0, stream>>>(ego, E, Esum);
  k_hist<<<9375, 256, 0, stream>>>(adj_rows, counts);
  k_scan1<<<147, 1024, 0, stream>>>(counts, row_start + 1, bsums);
  k_scan2<<<1, 256, 0, stream>>>(bsums, 147);
  k_scan3<<<147, 1024, 0, stream>>>(row_start, cursor, bsums);
  k_scatter<<<9375, 256, 0, stream>>>(adj_rows, adj_cols, adj_vals, cursor, sedge);

  for (int l = 0; l < 2; ++l) {
    k_spmm<<<37500, 256, 0, stream>>>(E, sedge, row_start, side);
    k_transform<<<TR_GRID, 256, 0, stream>>>(gc_w + l * 4096, gc_b + l * 64,
                                             bi_w + l * 4096, bi_b + l * 64,
                                             E, Esum, side);
  }

  k_gather<<<4096, 128, 0, stream>>>(Esum, user_id, item_id, ue, ie);

  dim3 ge(4096, 3);
  k_encoder<<<ge, 256, 0, stream>>>(ue, uh_w, uh_b, ud_w1, ud_b1, ud_w2, ud_b2, recs_u);
  k_encoder<<<ge, 256, 0, stream>>>(ie, ih_w, ih_b, id_w1, id_b1, id_w2, id_b2, recs_i);

  k_attn<<<512, 256, 0, stream>>>(recs_u, q_w, q_b, k_w, k_b, v_w, v_b, att_u);
  k_attn<<<512, 256, 0, stream>>>(recs_i, q_w, q_b, k_w, k_b, v_w, v_b, att_i);

  k_noise<<<3072, 256, 0, stream>>>(att_u, att_i, ku0, ku1, ki0, ki1, n1, n2, posdot);

  dim3 gt(8, 16, 6);
  k_ttl<<<gt, 256, 0, stream>>>(n1, n2, ttl);
  k_clred<<<1, 1024, 0, stream>>>(ttl, posdot, outp);

  k_head<<<1024, 256, 0, stream>>>(att_u, att_i, skills, dg_w1, dg_b1, dg_w2, dg_b2,
                                   pr_w, pr_b, outp);
}